// Round 10
// baseline (278.560 us; speedup 1.0000x reference)
//
#include <hip/hip_runtime.h>
#include <hip/hip_bf16.h>

// ARMANet: 2x ARMAConv(K=1,T=1) + global mean pool + FC
// N=100000 nodes, E=1600000 edges, IN=HID=64, OUT=32, G=64 graphs.
// R29 = R28 + scan-free/stage-free bucket_kernel.
//  Accounting (R25/R28 cross-check): bucket+csr build ~110-125us -- largest
//  block in the pipeline, invisible in top-5 (slots all gather_gemm iters).
//  bucket_kernel overhaul: the 16-barrier intra-block scan + 12KB stage +
//  3rd pass existed only to coalesce bpack writes. Replaced with direct
//  scattered writes: gbase[bk]=atomicAdd(&bcnt[bk],hist[bk]); slot =
//  gbase+atomicAdd(&cur[bk],1). 3 barriers (was ~20), LDS 3.2KB (was 22.5).
//  bpack intra-bucket order changes; csr counting sort is order-insensitive
//  (R21/R22: totally different orderings -> identical absmax 0.0002441406).
//  csr_gemm, gather_gemm, gather_pool, final_fc: byte-identical to R28
//  (271.6us best).

#define NB 256
#define CAP 5120
#define MAXB 400
#define P1_CHUNK 2048

typedef unsigned int uint32;
typedef unsigned short ushort16;
typedef __attribute__((ext_vector_type(8))) short short8;   // 8 bf16 (4 VGPRs)
typedef __attribute__((ext_vector_type(4))) float f32x4;    // MFMA C/D

__device__ inline uint32 bf16rn(float f) {
    uint32 u = __float_as_uint(f);
    uint32 r = ((u >> 16) & 1u) + 0x7FFFu;
    return (u + r) >> 16;
}
__device__ inline uint32 pack_bf16(float a, float b) {
    return bf16rn(a) | (bf16rn(b) << 16);
}
__device__ inline float bflo(uint32 u) { return __uint_as_float(u << 16); }
__device__ inline float bfhi(uint32 u) { return __uint_as_float(u & 0xFFFF0000u); }

// ---------------- stage 1: bucket edges by destination (+ fused weight prep) ----------------
// blocks [0,128): weights -> transposed split-bf16 table wt[m][d*64+k].
// blocks [128,...): 2048-edge chunks; direct scattered bpack writes.
__global__ __launch_bounds__(256) void bucket_kernel(
    const int* __restrict__ row, const int* __restrict__ col,
    uint32* __restrict__ bpack, int* __restrict__ bcnt, int E,
    const float* __restrict__ W1i, const float* __restrict__ W1r,
    const float* __restrict__ W2i, const float* __restrict__ W2r,
    ushort16* __restrict__ wt) {
    __shared__ int hist[MAXB];    // histogram, then reused as cur
    __shared__ int gbase[MAXB];

    int t = threadIdx.x;

    if (blockIdx.x < 128) {
        // ---- wprep role ----
        int idx = blockIdx.x * 256 + t;     // 8*4096 items over 128 blocks
        int m = idx >> 12;
        int r = idx & 4095;
        int d = r >> 6, k = r & 63;
        const float* W = (m < 2) ? W1i : (m < 4) ? W1r : (m < 6) ? W2i : W2r;
        float v = W[k * 64 + d];
        uint32 hi = bf16rn(v);
        uint32 outv;
        if (m & 1) {
            float hf = __uint_as_float(hi << 16);
            outv = bf16rn(v - hf);
        } else {
            outv = hi;
        }
        wt[(size_t)m * 4096 + d * 64 + k] = (unsigned short)outv;
        return;
    }

    for (int i = t; i < MAXB; i += 256) hist[i] = 0;
    __syncthreads();

    int e0 = (blockIdx.x - 128) * P1_CHUNK;
    int cntE = min(E - e0, P1_CHUNK);

    for (int i = t; i < cntE; i += 256) {
        int c = col[e0 + i];
        atomicAdd(&hist[c >> 8], 1);
    }
    __syncthreads();

    for (int i = t; i < MAXB; i += 256) {
        int hc = hist[i];
        gbase[i] = hc ? atomicAdd(&bcnt[i], hc) : 0;
        hist[i] = 0;              // becomes per-block cur
    }
    __syncthreads();

    for (int i = t; i < cntE; i += 256) {
        int c = col[e0 + i];
        int r = row[e0 + i];
        int bk = c >> 8;
        int k = atomicAdd(&hist[bk], 1);
        int gd = gbase[bk] + k;
        if (gd < CAP)
            bpack[(size_t)bk * CAP + gd] = ((uint32)(c & 255) << 24) | (uint32)r;
    }
}

// ---------------- stage 2: per-bucket counting sort -> CSR + dinv, FUSED layer-1 gemm ----------------
__global__ __launch_bounds__(1024) void csr_gemm(
    const uint32* __restrict__ bpack, const int* __restrict__ bcnt,
    int* __restrict__ es, int* __restrict__ nstart, int* __restrict__ ndeg,
    float* __restrict__ dinv,
    const float* __restrict__ X, const ushort16* __restrict__ wt4,
    const float* __restrict__ bias,
    ushort16* __restrict__ Ts, ushort16* __restrict__ Rs, int n) {
    __shared__ int h[NB];
    __shared__ alignas(16) unsigned char uni[36864];   // max(csr 22.5KB, sXs 36.9KB)
    uint32* sbp = (uint32*)uni;                         // [CAP]   20480 B
    int* s      = (int*)(uni + 20480);                  // [NB]
    int* cur    = (int*)(uni + 21504);                  // [NB]
    unsigned short* sXs = (unsigned short*)uni;         // [4][64*72] phase B

    int b = blockIdx.x, t = threadIdx.x;
    if (t < NB) h[t] = 0;
    __syncthreads();
    int cnt = min(bcnt[b], CAP);
    size_t base = (size_t)b * CAP;
    for (int i = t; i < cnt; i += 1024) {
        uint32 pk = bpack[base + i];
        sbp[i] = pk;
        atomicAdd(&h[pk >> 24], 1);
    }
    __syncthreads();
    if (t < NB) s[t] = h[t];
    __syncthreads();
    for (int off = 1; off < NB; off <<= 1) {
        int x = 0;
        if (t < NB && t >= off) x = s[t - off];
        __syncthreads();
        if (t < NB) s[t] += x;
        __syncthreads();
    }
    if (t < NB) {
        int myofs = s[t] - h[t];
        cur[t] = myofs;
        int node = b * NB + t;
        if (node < n) {
            nstart[node] = (int)base + myofs;
            ndeg[node] = h[t];
            dinv[node] = h[t] ? rsqrtf((float)h[t]) : 0.0f;
        }
    }
    __syncthreads();
    for (int i = t; i < cnt; i += 1024) {
        uint32 pk = sbp[i];
        int cl = (int)(pk >> 24);
        int p = atomicAdd(&cur[cl], 1);
        es[base + p] = (int)(pk & 0xFFFFFFu);
    }
    __syncthreads();   // sbp fully consumed; union switches to sXs

    // ---- Phase B: stage X (4 tiles x [64 rows x 72 bf16]) ----
    for (int i = t; i < 4096; i += 1024) {
        int tile = i >> 10, j = i & 1023;
        int r = j >> 4, c4 = (j & 15) * 4;
        int node = b * NB + tile * 64 + r;
        float4 v = make_float4(0.f, 0.f, 0.f, 0.f);
        if (node < n) v = *(const float4*)&X[(size_t)node * 64 + c4];
        *(uint32*)&sXs[tile * 4608 + r * 72 + c4] = pack_bf16(v.x, v.y);
        *(uint32*)&sXs[tile * 4608 + r * 72 + c4 + 2] = pack_bf16(v.z, v.w);
    }
    __syncthreads();

    // ---- MFMA: wave wv -> tile wv>>2, dim-quadrant wv&3 ----
    int wv = t >> 6, lane = t & 63;
    int tile = wv >> 2, wq = wv & 3;
    int q = lane >> 4, colx = lane & 15;
    int dim = wq * 16 + colx;

    short8 bih[2], bil[2], brh[2], brl[2];
#pragma unroll
    for (int kh = 0; kh < 2; ++kh) {
        size_t o = (size_t)dim * 64 + kh * 32 + q * 8;
        bih[kh] = *(const short8*)&wt4[0 * 4096 + o];
        bil[kh] = *(const short8*)&wt4[1 * 4096 + o];
        brh[kh] = *(const short8*)&wt4[2 * 4096 + o];
        brl[kh] = *(const short8*)&wt4[3 * 4096 + o];
    }
    float4 bias4 = *(const float4*)&bias[wq * 16 + q * 4];

    unsigned short* TsU = (unsigned short*)Ts;
    unsigned short* RsU = (unsigned short*)Rs;

#pragma unroll
    for (int mt = 0; mt < 4; ++mt) {
        int rbase = mt * 16 + colx;
        short8 a0 = *(const short8*)&sXs[tile * 4608 + rbase * 72 + q * 8];
        short8 a1 = *(const short8*)&sXs[tile * 4608 + rbase * 72 + 32 + q * 8];
        f32x4 accT = {0.f, 0.f, 0.f, 0.f};
        f32x4 accR = {0.f, 0.f, 0.f, 0.f};
        accT = __builtin_amdgcn_mfma_f32_16x16x32_bf16(bih[0], a0, accT, 0, 0, 0);
        accT = __builtin_amdgcn_mfma_f32_16x16x32_bf16(bih[1], a1, accT, 0, 0, 0);
        accT = __builtin_amdgcn_mfma_f32_16x16x32_bf16(bil[0], a0, accT, 0, 0, 0);
        accT = __builtin_amdgcn_mfma_f32_16x16x32_bf16(bil[1], a1, accT, 0, 0, 0);
        accR = __builtin_amdgcn_mfma_f32_16x16x32_bf16(brh[0], a0, accR, 0, 0, 0);
        accR = __builtin_amdgcn_mfma_f32_16x16x32_bf16(brh[1], a1, accR, 0, 0, 0);
        accR = __builtin_amdgcn_mfma_f32_16x16x32_bf16(brl[0], a0, accR, 0, 0, 0);
        accR = __builtin_amdgcn_mfma_f32_16x16x32_bf16(brl[1], a1, accR, 0, 0, 0);

        int li = tile * 64 + mt * 16 + colx;
        int node = b * NB + li;
        if (node < n) {
            int dg = h[li];
            float dv = dg ? rsqrtf((float)dg) : 0.0f;   // identical to csr dinv
            uint2 pT, pR;
            pT.x = pack_bf16(accT[0] * dv, accT[1] * dv);
            pT.y = pack_bf16(accT[2] * dv, accT[3] * dv);
            pR.x = pack_bf16(accR[0] + bias4.x, accR[1] + bias4.y);
            pR.y = pack_bf16(accR[2] + bias4.z, accR[3] + bias4.w);
            size_t o = (size_t)node * 64 + wq * 16 + q * 4;
            *(uint2*)&TsU[o] = pT;
            *(uint2*)&RsU[o] = pR;
        }
    }
}

// ---------------- gather1 + layer-2 gemm fused ----------------
__global__ __launch_bounds__(256) void gather_gemm(
    const uint2* __restrict__ Ts2, const uint2* __restrict__ Rs2,
    const int* __restrict__ es, const int* __restrict__ nstart,
    const int* __restrict__ ndeg, const float* __restrict__ dinv,
    const ushort16* __restrict__ wt4, const float* __restrict__ bias,
    ushort16* __restrict__ To, ushort16* __restrict__ Ro, int n) {
    __shared__ unsigned short sHs[64 * 72];   // 9216 B
    int t = threadIdx.x;
    int w = t >> 6, lane = t & 63;
    int q = lane >> 4, d4 = lane & 15;
    int node0 = blockIdx.x * 64;

    for (int rd = 0; rd < 16; ++rd) {
        int cl = w * 16 + rd;
        int c = node0 + cl;
        if (c < n) {
            int deg = ndeg[c];
            int s0 = nstart[c];
            float a0 = 0.f, a1 = 0.f, a2 = 0.f, a3 = 0.f;
            for (int base = 0; base < deg; base += 64) {
                int m = min(deg - base, 64);
                int sid = (lane < m) ? es[s0 + base + lane] : 0;
                for (int j = 0; j < m; j += 16) {
                    int e0 = j + q, e1 = j + 4 + q, e2 = j + 8 + q, e3 = j + 12 + q;
                    int r0 = __shfl(sid, e0);
                    int r1 = __shfl(sid, e1);
                    int r2 = __shfl(sid, e2);
                    int r3 = __shfl(sid, e3);
                    uint2 z = make_uint2(0u, 0u);
                    uint2 v0 = (e0 < m) ? Ts2[(size_t)r0 * 16 + d4] : z;
                    uint2 v1 = (e1 < m) ? Ts2[(size_t)r1 * 16 + d4] : z;
                    uint2 v2 = (e2 < m) ? Ts2[(size_t)r2 * 16 + d4] : z;
                    uint2 v3 = (e3 < m) ? Ts2[(size_t)r3 * 16 + d4] : z;
                    a0 += bflo(v0.x) + bflo(v1.x) + bflo(v2.x) + bflo(v3.x);
                    a1 += bfhi(v0.x) + bfhi(v1.x) + bfhi(v2.x) + bfhi(v3.x);
                    a2 += bflo(v0.y) + bflo(v1.y) + bflo(v2.y) + bflo(v3.y);
                    a3 += bfhi(v0.y) + bfhi(v1.y) + bfhi(v2.y) + bfhi(v3.y);
                }
            }
            a0 += __shfl_xor(a0, 16); a0 += __shfl_xor(a0, 32);
            a1 += __shfl_xor(a1, 16); a1 += __shfl_xor(a1, 32);
            a2 += __shfl_xor(a2, 16); a2 += __shfl_xor(a2, 32);
            a3 += __shfl_xor(a3, 16); a3 += __shfl_xor(a3, 32);
            if (lane < 16) {
                float dc = dinv[c];
                uint2 ur = Rs2[(size_t)c * 16 + d4];
                float h0 = fmaxf(fmaf(dc, a0, bflo(ur.x)), 0.0f);
                float h1 = fmaxf(fmaf(dc, a1, bfhi(ur.x)), 0.0f);
                float h2 = fmaxf(fmaf(dc, a2, bflo(ur.y)), 0.0f);
                float h3 = fmaxf(fmaf(dc, a3, bfhi(ur.y)), 0.0f);
                *(uint2*)&sHs[cl * 72 + d4 * 4] =
                    make_uint2(pack_bf16(h0, h1), pack_bf16(h2, h3));
            }
        } else {
            if (lane < 16)
                *(uint2*)&sHs[cl * 72 + d4 * 4] = make_uint2(0u, 0u);
        }
    }
    __syncthreads();

    // ---- layer-2 gemm (original 256-thr body, reads sHs) ----
    int colx = lane & 15;
    int dim = w * 16 + colx;

    short8 bih[2], bil[2], brh[2], brl[2];
#pragma unroll
    for (int kh = 0; kh < 2; ++kh) {
        size_t o = (size_t)dim * 64 + kh * 32 + q * 8;
        bih[kh] = *(const short8*)&wt4[0 * 4096 + o];
        bil[kh] = *(const short8*)&wt4[1 * 4096 + o];
        brh[kh] = *(const short8*)&wt4[2 * 4096 + o];
        brl[kh] = *(const short8*)&wt4[3 * 4096 + o];
    }
    float4 bias4 = *(const float4*)&bias[w * 16 + q * 4];

    unsigned short* ToU = (unsigned short*)To;
    unsigned short* RoU = (unsigned short*)Ro;

#pragma unroll
    for (int mt = 0; mt < 4; ++mt) {
        int rbase = mt * 16 + colx;
        short8 a0 = *(const short8*)&sHs[rbase * 72 + q * 8];
        short8 a1 = *(const short8*)&sHs[rbase * 72 + 32 + q * 8];
        f32x4 accT = {0.f, 0.f, 0.f, 0.f};
        f32x4 accR = {0.f, 0.f, 0.f, 0.f};
        accT = __builtin_amdgcn_mfma_f32_16x16x32_bf16(bih[0], a0, accT, 0, 0, 0);
        accT = __builtin_amdgcn_mfma_f32_16x16x32_bf16(bih[1], a1, accT, 0, 0, 0);
        accT = __builtin_amdgcn_mfma_f32_16x16x32_bf16(bil[0], a0, accT, 0, 0, 0);
        accT = __builtin_amdgcn_mfma_f32_16x16x32_bf16(bil[1], a1, accT, 0, 0, 0);
        accR = __builtin_amdgcn_mfma_f32_16x16x32_bf16(brh[0], a0, accR, 0, 0, 0);
        accR = __builtin_amdgcn_mfma_f32_16x16x32_bf16(brh[1], a1, accR, 0, 0, 0);
        accR = __builtin_amdgcn_mfma_f32_16x16x32_bf16(brl[0], a0, accR, 0, 0, 0);
        accR = __builtin_amdgcn_mfma_f32_16x16x32_bf16(brl[1], a1, accR, 0, 0, 0);

        int node = node0 + mt * 16 + colx;
        if (node < n) {
            float dv = dinv[node];
            uint2 pT, pR;
            pT.x = pack_bf16(accT[0] * dv, accT[1] * dv);
            pT.y = pack_bf16(accT[2] * dv, accT[3] * dv);
            pR.x = pack_bf16(accR[0] + bias4.x, accR[1] + bias4.y);
            pR.y = pack_bf16(accR[2] + bias4.z, accR[3] + bias4.w);
            size_t o = (size_t)node * 64 + w * 16 + q * 4;
            *(uint2*)&ToU[o] = pT;
            *(uint2*)&RoU[o] = pR;
        }
    }
}

// ---------------- gather2 + mean-pool fused (H never materialized) ----------------
__global__ __launch_bounds__(256) void gather_pool(
    const uint2* __restrict__ Ts2, const uint2* __restrict__ Rs2,
    const int* __restrict__ es, const int* __restrict__ nstart,
    const int* __restrict__ ndeg, const float* __restrict__ dinv,
    const int* __restrict__ batch,
    float* __restrict__ pooled, float* __restrict__ cnt, int n) {
    __shared__ float sAcc[64 * 64];   // 16 KB
    __shared__ float sCnt[64];
    int t = threadIdx.x;
    for (int i = t; i < 4096; i += 256) sAcc[i] = 0.0f;
    if (t < 64) sCnt[t] = 0.0f;
    __syncthreads();

    int w = t >> 6, lane = t & 63;
    int q = lane >> 4, d4 = lane & 15;
    int node0 = blockIdx.x * 64;

    int gcur = -1;
    float p0 = 0.f, p1 = 0.f, p2 = 0.f, p3 = 0.f, pc = 0.f;

    for (int rd = 0; rd < 16; ++rd) {
        int c = node0 + w * 16 + rd;
        if (c < n) {
            int g = batch[c];
            if (g != gcur) {                     // wave-uniform branch
                if (gcur >= 0 && lane < 16) {
                    atomicAdd(&sAcc[gcur * 64 + d4 * 4 + 0], p0);
                    atomicAdd(&sAcc[gcur * 64 + d4 * 4 + 1], p1);
                    atomicAdd(&sAcc[gcur * 64 + d4 * 4 + 2], p2);
                    atomicAdd(&sAcc[gcur * 64 + d4 * 4 + 3], p3);
                    if (d4 == 0) atomicAdd(&sCnt[gcur], pc);
                }
                gcur = g;
                p0 = p1 = p2 = p3 = 0.f; pc = 0.f;
            }
            int deg = ndeg[c];
            int s0 = nstart[c];
            float a0 = 0.f, a1 = 0.f, a2 = 0.f, a3 = 0.f;
            for (int base = 0; base < deg; base += 64) {
                int m = min(deg - base, 64);
                int sid = (lane < m) ? es[s0 + base + lane] : 0;
                for (int j = 0; j < m; j += 16) {
                    int e0 = j + q, e1 = j + 4 + q, e2 = j + 8 + q, e3 = j + 12 + q;
                    int r0 = __shfl(sid, e0);
                    int r1 = __shfl(sid, e1);
                    int r2 = __shfl(sid, e2);
                    int r3 = __shfl(sid, e3);
                    uint2 z = make_uint2(0u, 0u);
                    uint2 v0 = (e0 < m) ? Ts2[(size_t)r0 * 16 + d4] : z;
                    uint2 v1 = (e1 < m) ? Ts2[(size_t)r1 * 16 + d4] : z;
                    uint2 v2 = (e2 < m) ? Ts2[(size_t)r2 * 16 + d4] : z;
                    uint2 v3 = (e3 < m) ? Ts2[(size_t)r3 * 16 + d4] : z;
                    a0 += bflo(v0.x) + bflo(v1.x) + bflo(v2.x) + bflo(v3.x);
                    a1 += bfhi(v0.x) + bfhi(v1.x) + bfhi(v2.x) + bfhi(v3.x);
                    a2 += bflo(v0.y) + bflo(v1.y) + bflo(v2.y) + bflo(v3.y);
                    a3 += bfhi(v0.y) + bfhi(v1.y) + bfhi(v2.y) + bfhi(v3.y);
                }
            }
            a0 += __shfl_xor(a0, 16); a0 += __shfl_xor(a0, 32);
            a1 += __shfl_xor(a1, 16); a1 += __shfl_xor(a1, 32);
            a2 += __shfl_xor(a2, 16); a2 += __shfl_xor(a2, 32);
            a3 += __shfl_xor(a3, 16); a3 += __shfl_xor(a3, 32);
            if (lane < 16) {
                float dc = dinv[c];
                uint2 ur = Rs2[(size_t)c * 16 + d4];
                float h0 = fmaxf(fmaf(dc, a0, bflo(ur.x)), 0.0f);
                float h1 = fmaxf(fmaf(dc, a1, bfhi(ur.x)), 0.0f);
                float h2 = fmaxf(fmaf(dc, a2, bflo(ur.y)), 0.0f);
                float h3 = fmaxf(fmaf(dc, a3, bfhi(ur.y)), 0.0f);
                // bf16 round-trip: accumulate exactly the bits old pool read
                uint2 hb = make_uint2(pack_bf16(h0, h1), pack_bf16(h2, h3));
                p0 += bflo(hb.x);
                p1 += bfhi(hb.x);
                p2 += bflo(hb.y);
                p3 += bfhi(hb.y);
                if (d4 == 0) pc += 1.0f;
            }
        }
    }
    if (gcur >= 0 && lane < 16) {
        atomicAdd(&sAcc[gcur * 64 + d4 * 4 + 0], p0);
        atomicAdd(&sAcc[gcur * 64 + d4 * 4 + 1], p1);
        atomicAdd(&sAcc[gcur * 64 + d4 * 4 + 2], p2);
        atomicAdd(&sAcc[gcur * 64 + d4 * 4 + 3], p3);
        if (d4 == 0) atomicAdd(&sCnt[gcur], pc);
    }
    __syncthreads();
    for (int i = t; i < 4096; i += 256) {
        float v = sAcc[i];
        if (v != 0.0f) atomicAdd(&pooled[i], v);
    }
    if (t < 64) {
        float v = sCnt[t];
        if (v != 0.0f) atomicAdd(&cnt[t], v);
    }
}

// ---------------- out[g,o] = (pooled[g,:]/max(cnt,1)) @ fcw + fcb ----------------
__global__ void final_fc(const float* __restrict__ pooled, const float* __restrict__ cnt,
                         const float* __restrict__ fcw, const float* __restrict__ fcb,
                         float* __restrict__ out) {
    int idx = blockIdx.x * 256 + threadIdx.x;
    if (idx >= 64 * 32) return;
    int g = idx >> 5, o = idx & 31;
    float c = fmaxf(cnt[g], 1.0f);
    float acc = 0.0f;
#pragma unroll
    for (int k = 0; k < 64; ++k) acc = fmaf(pooled[g * 64 + k], fcw[k * 32 + o], acc);
    out[idx] = acc / c + fcb[o];
}

extern "C" void kernel_launch(void* const* d_in, const int* in_sizes, int n_in,
                              void* d_out, int out_size, void* d_ws, size_t ws_size,
                              hipStream_t stream) {
    const float* x       = (const float*)d_in[0];
    const int*   eidx    = (const int*)d_in[1];
    const int*   batch   = (const int*)d_in[2];
    const float* w1_init = (const float*)d_in[3];
    const float* w1_root = (const float*)d_in[4];
    const float* b1      = (const float*)d_in[5];
    const float* w2_init = (const float*)d_in[6];
    const float* w2_root = (const float*)d_in[7];
    const float* b2      = (const float*)d_in[8];
    const float* fc_w    = (const float*)d_in[9];
    const float* fc_b    = (const float*)d_in[10];
    float* out = (float*)d_out;

    const int N = in_sizes[0] / 64;
    const int E = in_sizes[1] / 2;
    const int* row = eidx;
    const int* col = eidx + E;

    const int B = (N + NB - 1) / NB;  // 391 buckets

    // workspace (4-byte units):
    // bpack(B*CAP) | es(B*CAP) | [zeroed: bcnt(MAXB) | pooled(4096) | cnt(64)]
    // | nstart(N) | ndeg(N) | dinv(N) | wt(16384) | Ts1(N*32) | Rs1(N*32)
    // | T2(N*32) | R2(N*32)
    uint32* bpack = (uint32*)d_ws;
    int*   es     = (int*)(bpack + (size_t)B * CAP);
    int*   bcnt   = es + (size_t)B * CAP;
    float* pooled = (float*)(bcnt + MAXB);
    float* cnt    = pooled + 64 * 64;
    int*   nstart = (int*)(cnt + 64);
    int*   ndeg   = nstart + N;
    float* dinv   = (float*)(ndeg + N);
    uint32* wtU   = (uint32*)(dinv + N);            // 16384 uints (64 KB)
    uint32* Ts1   = wtU + 16384;                    // N*32
    uint32* Rs1   = Ts1 + (size_t)N * 32;           // N*32
    uint32* T2    = Rs1 + (size_t)N * 32;           // N*32
    uint32* R2    = T2 + (size_t)N * 32;            // N*32
    ushort16* wt  = (ushort16*)wtU;

    hipMemsetAsync(bcnt, 0, (size_t)(MAXB + 64 * 64 + 64) * sizeof(int), stream);

    // bucket + fused weight prep
    const int EB = (E + P1_CHUNK - 1) / P1_CHUNK;
    bucket_kernel<<<128 + EB, 256, 0, stream>>>(row, col, bpack, bcnt, E,
                                                w1_init, w1_root, w2_init, w2_root, wt);

    // CSR build + fused layer-1 gemm
    csr_gemm<<<B, 1024, 0, stream>>>(bpack, bcnt, es, nstart, ndeg, dinv,
                                     x, wt, b1, (ushort16*)Ts1, (ushort16*)Rs1, N);

    // gather1 + fused layer-2 gemm
    gather_gemm<<<(N + 63) / 64, 256, 0, stream>>>(
        (const uint2*)Ts1, (const uint2*)Rs1, es, nstart, ndeg, dinv,
        wt + (size_t)4 * 4096, b2, (ushort16*)T2, (ushort16*)R2, N);

    // gather2 + mean-pool (H never materialized)
    gather_pool<<<(N + 63) / 64, 256, 0, stream>>>(
        (const uint2*)T2, (const uint2*)R2, es, nstart, ndeg, dinv,
        batch, pooled, cnt, N);

    // FC
    final_fc<<<(64 * 32 + 255) / 256, 256, 0, stream>>>(pooled, cnt, fc_w, fc_b, out);
}

// Round 13
// 272.987 us; speedup vs baseline: 1.0204x; 1.0204x over previous
//
#include <hip/hip_runtime.h>
#include <hip/hip_bf16.h>

// ARMANet: 2x ARMAConv(K=1,T=1) + global mean pool + FC
// N=100000 nodes, E=1600000 edges, IN=HID=64, OUT=32, G=64 graphs.
// R32 = R28/R31 resubmitted verbatim (R12 bench was a container-acquisition
// failure; this exact source measured 271.6us / absmax 0.0002441406 in R9).
//  Session ledger:
//  - R30 cooperative mega-kernel: silent launch failure. Closed.
//  - R29 scan-free bucket: +7.0us. Reverted.
//  - R23 global-atomic CSR build: +430us. R21/R22 push-gather: 2-13x worse.
//  - Proven config: staged bucket(+wprep), csr+gemm1 fused, gather1+gemm2
//    fused, gather2+pool fused (H never materialized), final_fc.
//  Dispatches: bucket, csr_gemm, gather_gemm, gather_pool, fc (5 + memset).

#define NB 256
#define CAP 5120
#define MAXB 400
#define P1_CHUNK 2048

typedef unsigned int uint32;
typedef unsigned short ushort16;
typedef __attribute__((ext_vector_type(8))) short short8;   // 8 bf16 (4 VGPRs)
typedef __attribute__((ext_vector_type(4))) float f32x4;    // MFMA C/D

__device__ inline uint32 bf16rn(float f) {
    uint32 u = __float_as_uint(f);
    uint32 r = ((u >> 16) & 1u) + 0x7FFFu;
    return (u + r) >> 16;
}
__device__ inline uint32 pack_bf16(float a, float b) {
    return bf16rn(a) | (bf16rn(b) << 16);
}
__device__ inline float bflo(uint32 u) { return __uint_as_float(u << 16); }
__device__ inline float bfhi(uint32 u) { return __uint_as_float(u & 0xFFFF0000u); }

// ---------------- stage 1: bucket edges by destination (+ fused weight prep) ----------------
__global__ __launch_bounds__(256) void bucket_kernel(
    const int* __restrict__ row, const int* __restrict__ col,
    uint32* __restrict__ bpack, int* __restrict__ bcnt, int E,
    const float* __restrict__ W1i, const float* __restrict__ W1r,
    const float* __restrict__ W2i, const float* __restrict__ W2r,
    ushort16* __restrict__ wt) {
    __shared__ int hist[MAXB];
    __shared__ int ofs[MAXB];
    __shared__ int cur[MAXB];
    __shared__ int gbase[MAXB];
    __shared__ int s[256];
    __shared__ uint32 stage[P1_CHUNK];
    __shared__ unsigned short stage_bk[P1_CHUNK];

    int t = threadIdx.x;

    if (blockIdx.x < 128) {
        // ---- wprep role ----
        int idx = blockIdx.x * 256 + t;     // 8*4096 items over 128 blocks
        int m = idx >> 12;
        int r = idx & 4095;
        int d = r >> 6, k = r & 63;
        const float* W = (m < 2) ? W1i : (m < 4) ? W1r : (m < 6) ? W2i : W2r;
        float v = W[k * 64 + d];
        uint32 hi = bf16rn(v);
        uint32 outv;
        if (m & 1) {
            float hf = __uint_as_float(hi << 16);
            outv = bf16rn(v - hf);
        } else {
            outv = hi;
        }
        wt[(size_t)m * 4096 + d * 64 + k] = (unsigned short)outv;
        return;
    }

    for (int i = t; i < MAXB; i += 256) hist[i] = 0;
    __syncthreads();

    int e0 = (blockIdx.x - 128) * P1_CHUNK;
    int cntE = min(E - e0, P1_CHUNK);

    for (int i = t; i < cntE; i += 256) {
        int c = col[e0 + i];
        atomicAdd(&hist[c >> 8], 1);
    }
    __syncthreads();

    int i2 = 2 * t;
    int a = (i2 < MAXB) ? hist[i2] : 0;
    int b = (i2 + 1 < MAXB) ? hist[i2 + 1] : 0;
    s[t] = a + b;
    __syncthreads();
    for (int off = 1; off < 256; off <<= 1) {
        int x = (t >= off) ? s[t - off] : 0;
        __syncthreads();
        s[t] += x;
        __syncthreads();
    }
    int excl = (t > 0) ? s[t - 1] : 0;
    if (i2 < MAXB) ofs[i2] = excl;
    if (i2 + 1 < MAXB) ofs[i2 + 1] = excl + a;
    __syncthreads();

    for (int i = t; i < MAXB; i += 256) {
        cur[i] = ofs[i];
        gbase[i] = hist[i] ? atomicAdd(&bcnt[i], hist[i]) : 0;
    }
    __syncthreads();

    for (int i = t; i < cntE; i += 256) {
        int c = col[e0 + i];
        int r = row[e0 + i];
        int bk = c >> 8;
        int k = atomicAdd(&cur[bk], 1);
        stage[k] = ((uint32)(c & 255) << 24) | (uint32)r;
        stage_bk[k] = (unsigned short)bk;
    }
    __syncthreads();

    for (int i = t; i < cntE; i += 256) {
        uint32 pk = stage[i];
        int bk = stage_bk[i];
        int gd = gbase[bk] + (i - ofs[bk]);
        if (gd < CAP) bpack[(size_t)bk * CAP + gd] = pk;
    }
}

// ---------------- stage 2: per-bucket counting sort -> CSR + dinv, FUSED layer-1 gemm ----------------
__global__ __launch_bounds__(1024) void csr_gemm(
    const uint32* __restrict__ bpack, const int* __restrict__ bcnt,
    int* __restrict__ es, int* __restrict__ nstart, int* __restrict__ ndeg,
    float* __restrict__ dinv,
    const float* __restrict__ X, const ushort16* __restrict__ wt4,
    const float* __restrict__ bias,
    ushort16* __restrict__ Ts, ushort16* __restrict__ Rs, int n) {
    __shared__ int h[NB];
    __shared__ alignas(16) unsigned char uni[36864];   // max(csr 22.5KB, sXs 36.9KB)
    uint32* sbp = (uint32*)uni;                         // [CAP]   20480 B
    int* s      = (int*)(uni + 20480);                  // [NB]
    int* cur    = (int*)(uni + 21504);                  // [NB]
    unsigned short* sXs = (unsigned short*)uni;         // [4][64*72] phase B

    int b = blockIdx.x, t = threadIdx.x;
    if (t < NB) h[t] = 0;
    __syncthreads();
    int cnt = min(bcnt[b], CAP);
    size_t base = (size_t)b * CAP;
    for (int i = t; i < cnt; i += 1024) {
        uint32 pk = bpack[base + i];
        sbp[i] = pk;
        atomicAdd(&h[pk >> 24], 1);
    }
    __syncthreads();
    if (t < NB) s[t] = h[t];
    __syncthreads();
    for (int off = 1; off < NB; off <<= 1) {
        int x = 0;
        if (t < NB && t >= off) x = s[t - off];
        __syncthreads();
        if (t < NB) s[t] += x;
        __syncthreads();
    }
    if (t < NB) {
        int myofs = s[t] - h[t];
        cur[t] = myofs;
        int node = b * NB + t;
        if (node < n) {
            nstart[node] = (int)base + myofs;
            ndeg[node] = h[t];
            dinv[node] = h[t] ? rsqrtf((float)h[t]) : 0.0f;
        }
    }
    __syncthreads();
    for (int i = t; i < cnt; i += 1024) {
        uint32 pk = sbp[i];
        int cl = (int)(pk >> 24);
        int p = atomicAdd(&cur[cl], 1);
        es[base + p] = (int)(pk & 0xFFFFFFu);
    }
    __syncthreads();   // sbp fully consumed; union switches to sXs

    // ---- Phase B: stage X (4 tiles x [64 rows x 72 bf16]) ----
    for (int i = t; i < 4096; i += 1024) {
        int tile = i >> 10, j = i & 1023;
        int r = j >> 4, c4 = (j & 15) * 4;
        int node = b * NB + tile * 64 + r;
        float4 v = make_float4(0.f, 0.f, 0.f, 0.f);
        if (node < n) v = *(const float4*)&X[(size_t)node * 64 + c4];
        *(uint32*)&sXs[tile * 4608 + r * 72 + c4] = pack_bf16(v.x, v.y);
        *(uint32*)&sXs[tile * 4608 + r * 72 + c4 + 2] = pack_bf16(v.z, v.w);
    }
    __syncthreads();

    // ---- MFMA: wave wv -> tile wv>>2, dim-quadrant wv&3 ----
    int wv = t >> 6, lane = t & 63;
    int tile = wv >> 2, wq = wv & 3;
    int q = lane >> 4, colx = lane & 15;
    int dim = wq * 16 + colx;

    short8 bih[2], bil[2], brh[2], brl[2];
#pragma unroll
    for (int kh = 0; kh < 2; ++kh) {
        size_t o = (size_t)dim * 64 + kh * 32 + q * 8;
        bih[kh] = *(const short8*)&wt4[0 * 4096 + o];
        bil[kh] = *(const short8*)&wt4[1 * 4096 + o];
        brh[kh] = *(const short8*)&wt4[2 * 4096 + o];
        brl[kh] = *(const short8*)&wt4[3 * 4096 + o];
    }
    float4 bias4 = *(const float4*)&bias[wq * 16 + q * 4];

    unsigned short* TsU = (unsigned short*)Ts;
    unsigned short* RsU = (unsigned short*)Rs;

#pragma unroll
    for (int mt = 0; mt < 4; ++mt) {
        int rbase = mt * 16 + colx;
        short8 a0 = *(const short8*)&sXs[tile * 4608 + rbase * 72 + q * 8];
        short8 a1 = *(const short8*)&sXs[tile * 4608 + rbase * 72 + 32 + q * 8];
        f32x4 accT = {0.f, 0.f, 0.f, 0.f};
        f32x4 accR = {0.f, 0.f, 0.f, 0.f};
        accT = __builtin_amdgcn_mfma_f32_16x16x32_bf16(bih[0], a0, accT, 0, 0, 0);
        accT = __builtin_amdgcn_mfma_f32_16x16x32_bf16(bih[1], a1, accT, 0, 0, 0);
        accT = __builtin_amdgcn_mfma_f32_16x16x32_bf16(bil[0], a0, accT, 0, 0, 0);
        accT = __builtin_amdgcn_mfma_f32_16x16x32_bf16(bil[1], a1, accT, 0, 0, 0);
        accR = __builtin_amdgcn_mfma_f32_16x16x32_bf16(brh[0], a0, accR, 0, 0, 0);
        accR = __builtin_amdgcn_mfma_f32_16x16x32_bf16(brh[1], a1, accR, 0, 0, 0);
        accR = __builtin_amdgcn_mfma_f32_16x16x32_bf16(brl[0], a0, accR, 0, 0, 0);
        accR = __builtin_amdgcn_mfma_f32_16x16x32_bf16(brl[1], a1, accR, 0, 0, 0);

        int li = tile * 64 + mt * 16 + colx;
        int node = b * NB + li;
        if (node < n) {
            int dg = h[li];
            float dv = dg ? rsqrtf((float)dg) : 0.0f;   // identical to csr dinv
            uint2 pT, pR;
            pT.x = pack_bf16(accT[0] * dv, accT[1] * dv);
            pT.y = pack_bf16(accT[2] * dv, accT[3] * dv);
            pR.x = pack_bf16(accR[0] + bias4.x, accR[1] + bias4.y);
            pR.y = pack_bf16(accR[2] + bias4.z, accR[3] + bias4.w);
            size_t o = (size_t)node * 64 + wq * 16 + q * 4;
            *(uint2*)&TsU[o] = pT;
            *(uint2*)&RsU[o] = pR;
        }
    }
}

// ---------------- gather1 + layer-2 gemm fused ----------------
__global__ __launch_bounds__(256) void gather_gemm(
    const uint2* __restrict__ Ts2, const uint2* __restrict__ Rs2,
    const int* __restrict__ es, const int* __restrict__ nstart,
    const int* __restrict__ ndeg, const float* __restrict__ dinv,
    const ushort16* __restrict__ wt4, const float* __restrict__ bias,
    ushort16* __restrict__ To, ushort16* __restrict__ Ro, int n) {
    __shared__ unsigned short sHs[64 * 72];   // 9216 B
    int t = threadIdx.x;
    int w = t >> 6, lane = t & 63;
    int q = lane >> 4, d4 = lane & 15;
    int node0 = blockIdx.x * 64;

    for (int rd = 0; rd < 16; ++rd) {
        int cl = w * 16 + rd;
        int c = node0 + cl;
        if (c < n) {
            int deg = ndeg[c];
            int s0 = nstart[c];
            float a0 = 0.f, a1 = 0.f, a2 = 0.f, a3 = 0.f;
            for (int base = 0; base < deg; base += 64) {
                int m = min(deg - base, 64);
                int sid = (lane < m) ? es[s0 + base + lane] : 0;
                for (int j = 0; j < m; j += 16) {
                    int e0 = j + q, e1 = j + 4 + q, e2 = j + 8 + q, e3 = j + 12 + q;
                    int r0 = __shfl(sid, e0);
                    int r1 = __shfl(sid, e1);
                    int r2 = __shfl(sid, e2);
                    int r3 = __shfl(sid, e3);
                    uint2 z = make_uint2(0u, 0u);
                    uint2 v0 = (e0 < m) ? Ts2[(size_t)r0 * 16 + d4] : z;
                    uint2 v1 = (e1 < m) ? Ts2[(size_t)r1 * 16 + d4] : z;
                    uint2 v2 = (e2 < m) ? Ts2[(size_t)r2 * 16 + d4] : z;
                    uint2 v3 = (e3 < m) ? Ts2[(size_t)r3 * 16 + d4] : z;
                    a0 += bflo(v0.x) + bflo(v1.x) + bflo(v2.x) + bflo(v3.x);
                    a1 += bfhi(v0.x) + bfhi(v1.x) + bfhi(v2.x) + bfhi(v3.x);
                    a2 += bflo(v0.y) + bflo(v1.y) + bflo(v2.y) + bflo(v3.y);
                    a3 += bfhi(v0.y) + bfhi(v1.y) + bfhi(v2.y) + bfhi(v3.y);
                }
            }
            a0 += __shfl_xor(a0, 16); a0 += __shfl_xor(a0, 32);
            a1 += __shfl_xor(a1, 16); a1 += __shfl_xor(a1, 32);
            a2 += __shfl_xor(a2, 16); a2 += __shfl_xor(a2, 32);
            a3 += __shfl_xor(a3, 16); a3 += __shfl_xor(a3, 32);
            if (lane < 16) {
                float dc = dinv[c];
                uint2 ur = Rs2[(size_t)c * 16 + d4];
                float h0 = fmaxf(fmaf(dc, a0, bflo(ur.x)), 0.0f);
                float h1 = fmaxf(fmaf(dc, a1, bfhi(ur.x)), 0.0f);
                float h2 = fmaxf(fmaf(dc, a2, bflo(ur.y)), 0.0f);
                float h3 = fmaxf(fmaf(dc, a3, bfhi(ur.y)), 0.0f);
                *(uint2*)&sHs[cl * 72 + d4 * 4] =
                    make_uint2(pack_bf16(h0, h1), pack_bf16(h2, h3));
            }
        } else {
            if (lane < 16)
                *(uint2*)&sHs[cl * 72 + d4 * 4] = make_uint2(0u, 0u);
        }
    }
    __syncthreads();

    // ---- layer-2 gemm (original 256-thr body, reads sHs) ----
    int colx = lane & 15;
    int dim = w * 16 + colx;

    short8 bih[2], bil[2], brh[2], brl[2];
#pragma unroll
    for (int kh = 0; kh < 2; ++kh) {
        size_t o = (size_t)dim * 64 + kh * 32 + q * 8;
        bih[kh] = *(const short8*)&wt4[0 * 4096 + o];
        bil[kh] = *(const short8*)&wt4[1 * 4096 + o];
        brh[kh] = *(const short8*)&wt4[2 * 4096 + o];
        brl[kh] = *(const short8*)&wt4[3 * 4096 + o];
    }
    float4 bias4 = *(const float4*)&bias[w * 16 + q * 4];

    unsigned short* ToU = (unsigned short*)To;
    unsigned short* RoU = (unsigned short*)Ro;

#pragma unroll
    for (int mt = 0; mt < 4; ++mt) {
        int rbase = mt * 16 + colx;
        short8 a0 = *(const short8*)&sHs[rbase * 72 + q * 8];
        short8 a1 = *(const short8*)&sHs[rbase * 72 + 32 + q * 8];
        f32x4 accT = {0.f, 0.f, 0.f, 0.f};
        f32x4 accR = {0.f, 0.f, 0.f, 0.f};
        accT = __builtin_amdgcn_mfma_f32_16x16x32_bf16(bih[0], a0, accT, 0, 0, 0);
        accT = __builtin_amdgcn_mfma_f32_16x16x32_bf16(bih[1], a1, accT, 0, 0, 0);
        accT = __builtin_amdgcn_mfma_f32_16x16x32_bf16(bil[0], a0, accT, 0, 0, 0);
        accT = __builtin_amdgcn_mfma_f32_16x16x32_bf16(bil[1], a1, accT, 0, 0, 0);
        accR = __builtin_amdgcn_mfma_f32_16x16x32_bf16(brh[0], a0, accR, 0, 0, 0);
        accR = __builtin_amdgcn_mfma_f32_16x16x32_bf16(brh[1], a1, accR, 0, 0, 0);
        accR = __builtin_amdgcn_mfma_f32_16x16x32_bf16(brl[0], a0, accR, 0, 0, 0);
        accR = __builtin_amdgcn_mfma_f32_16x16x32_bf16(brl[1], a1, accR, 0, 0, 0);

        int node = node0 + mt * 16 + colx;
        if (node < n) {
            float dv = dinv[node];
            uint2 pT, pR;
            pT.x = pack_bf16(accT[0] * dv, accT[1] * dv);
            pT.y = pack_bf16(accT[2] * dv, accT[3] * dv);
            pR.x = pack_bf16(accR[0] + bias4.x, accR[1] + bias4.y);
            pR.y = pack_bf16(accR[2] + bias4.z, accR[3] + bias4.w);
            size_t o = (size_t)node * 64 + w * 16 + q * 4;
            *(uint2*)&ToU[o] = pT;
            *(uint2*)&RoU[o] = pR;
        }
    }
}

// ---------------- gather2 + mean-pool fused (H never materialized) ----------------
__global__ __launch_bounds__(256) void gather_pool(
    const uint2* __restrict__ Ts2, const uint2* __restrict__ Rs2,
    const int* __restrict__ es, const int* __restrict__ nstart,
    const int* __restrict__ ndeg, const float* __restrict__ dinv,
    const int* __restrict__ batch,
    float* __restrict__ pooled, float* __restrict__ cnt, int n) {
    __shared__ float sAcc[64 * 64];   // 16 KB
    __shared__ float sCnt[64];
    int t = threadIdx.x;
    for (int i = t; i < 4096; i += 256) sAcc[i] = 0.0f;
    if (t < 64) sCnt[t] = 0.0f;
    __syncthreads();

    int w = t >> 6, lane = t & 63;
    int q = lane >> 4, d4 = lane & 15;
    int node0 = blockIdx.x * 64;

    int gcur = -1;
    float p0 = 0.f, p1 = 0.f, p2 = 0.f, p3 = 0.f, pc = 0.f;

    for (int rd = 0; rd < 16; ++rd) {
        int c = node0 + w * 16 + rd;
        if (c < n) {
            int g = batch[c];
            if (g != gcur) {                     // wave-uniform branch
                if (gcur >= 0 && lane < 16) {
                    atomicAdd(&sAcc[gcur * 64 + d4 * 4 + 0], p0);
                    atomicAdd(&sAcc[gcur * 64 + d4 * 4 + 1], p1);
                    atomicAdd(&sAcc[gcur * 64 + d4 * 4 + 2], p2);
                    atomicAdd(&sAcc[gcur * 64 + d4 * 4 + 3], p3);
                    if (d4 == 0) atomicAdd(&sCnt[gcur], pc);
                }
                gcur = g;
                p0 = p1 = p2 = p3 = 0.f; pc = 0.f;
            }
            int deg = ndeg[c];
            int s0 = nstart[c];
            float a0 = 0.f, a1 = 0.f, a2 = 0.f, a3 = 0.f;
            for (int base = 0; base < deg; base += 64) {
                int m = min(deg - base, 64);
                int sid = (lane < m) ? es[s0 + base + lane] : 0;
                for (int j = 0; j < m; j += 16) {
                    int e0 = j + q, e1 = j + 4 + q, e2 = j + 8 + q, e3 = j + 12 + q;
                    int r0 = __shfl(sid, e0);
                    int r1 = __shfl(sid, e1);
                    int r2 = __shfl(sid, e2);
                    int r3 = __shfl(sid, e3);
                    uint2 z = make_uint2(0u, 0u);
                    uint2 v0 = (e0 < m) ? Ts2[(size_t)r0 * 16 + d4] : z;
                    uint2 v1 = (e1 < m) ? Ts2[(size_t)r1 * 16 + d4] : z;
                    uint2 v2 = (e2 < m) ? Ts2[(size_t)r2 * 16 + d4] : z;
                    uint2 v3 = (e3 < m) ? Ts2[(size_t)r3 * 16 + d4] : z;
                    a0 += bflo(v0.x) + bflo(v1.x) + bflo(v2.x) + bflo(v3.x);
                    a1 += bfhi(v0.x) + bfhi(v1.x) + bfhi(v2.x) + bfhi(v3.x);
                    a2 += bflo(v0.y) + bflo(v1.y) + bflo(v2.y) + bflo(v3.y);
                    a3 += bfhi(v0.y) + bfhi(v1.y) + bfhi(v2.y) + bfhi(v3.y);
                }
            }
            a0 += __shfl_xor(a0, 16); a0 += __shfl_xor(a0, 32);
            a1 += __shfl_xor(a1, 16); a1 += __shfl_xor(a1, 32);
            a2 += __shfl_xor(a2, 16); a2 += __shfl_xor(a2, 32);
            a3 += __shfl_xor(a3, 16); a3 += __shfl_xor(a3, 32);
            if (lane < 16) {
                float dc = dinv[c];
                uint2 ur = Rs2[(size_t)c * 16 + d4];
                float h0 = fmaxf(fmaf(dc, a0, bflo(ur.x)), 0.0f);
                float h1 = fmaxf(fmaf(dc, a1, bfhi(ur.x)), 0.0f);
                float h2 = fmaxf(fmaf(dc, a2, bflo(ur.y)), 0.0f);
                float h3 = fmaxf(fmaf(dc, a3, bfhi(ur.y)), 0.0f);
                // bf16 round-trip: accumulate exactly the bits old pool read
                uint2 hb = make_uint2(pack_bf16(h0, h1), pack_bf16(h2, h3));
                p0 += bflo(hb.x);
                p1 += bfhi(hb.x);
                p2 += bflo(hb.y);
                p3 += bfhi(hb.y);
                if (d4 == 0) pc += 1.0f;
            }
        }
    }
    if (gcur >= 0 && lane < 16) {
        atomicAdd(&sAcc[gcur * 64 + d4 * 4 + 0], p0);
        atomicAdd(&sAcc[gcur * 64 + d4 * 4 + 1], p1);
        atomicAdd(&sAcc[gcur * 64 + d4 * 4 + 2], p2);
        atomicAdd(&sAcc[gcur * 64 + d4 * 4 + 3], p3);
        if (d4 == 0) atomicAdd(&sCnt[gcur], pc);
    }
    __syncthreads();
    for (int i = t; i < 4096; i += 256) {
        float v = sAcc[i];
        if (v != 0.0f) atomicAdd(&pooled[i], v);
    }
    if (t < 64) {
        float v = sCnt[t];
        if (v != 0.0f) atomicAdd(&cnt[t], v);
    }
}

// ---------------- out[g,o] = (pooled[g,:]/max(cnt,1)) @ fcw + fcb ----------------
__global__ void final_fc(const float* __restrict__ pooled, const float* __restrict__ cnt,
                         const float* __restrict__ fcw, const float* __restrict__ fcb,
                         float* __restrict__ out) {
    int idx = blockIdx.x * 256 + threadIdx.x;
    if (idx >= 64 * 32) return;
    int g = idx >> 5, o = idx & 31;
    float c = fmaxf(cnt[g], 1.0f);
    float acc = 0.0f;
#pragma unroll
    for (int k = 0; k < 64; ++k) acc = fmaf(pooled[g * 64 + k], fcw[k * 32 + o], acc);
    out[idx] = acc / c + fcb[o];
}

extern "C" void kernel_launch(void* const* d_in, const int* in_sizes, int n_in,
                              void* d_out, int out_size, void* d_ws, size_t ws_size,
                              hipStream_t stream) {
    const float* x       = (const float*)d_in[0];
    const int*   eidx    = (const int*)d_in[1];
    const int*   batch   = (const int*)d_in[2];
    const float* w1_init = (const float*)d_in[3];
    const float* w1_root = (const float*)d_in[4];
    const float* b1      = (const float*)d_in[5];
    const float* w2_init = (const float*)d_in[6];
    const float* w2_root = (const float*)d_in[7];
    const float* b2      = (const float*)d_in[8];
    const float* fc_w    = (const float*)d_in[9];
    const float* fc_b    = (const float*)d_in[10];
    float* out = (float*)d_out;

    const int N = in_sizes[0] / 64;
    const int E = in_sizes[1] / 2;
    const int* row = eidx;
    const int* col = eidx + E;

    const int B = (N + NB - 1) / NB;  // 391 buckets

    // workspace (4-byte units):
    // bpack(B*CAP) | es(B*CAP) | [zeroed: bcnt(MAXB) | pooled(4096) | cnt(64)]
    // | nstart(N) | ndeg(N) | dinv(N) | wt(16384) | Ts1(N*32) | Rs1(N*32)
    // | T2(N*32) | R2(N*32)
    uint32* bpack = (uint32*)d_ws;
    int*   es     = (int*)(bpack + (size_t)B * CAP);
    int*   bcnt   = es + (size_t)B * CAP;
    float* pooled = (float*)(bcnt + MAXB);
    float* cnt    = pooled + 64 * 64;
    int*   nstart = (int*)(cnt + 64);
    int*   ndeg   = nstart + N;
    float* dinv   = (float*)(ndeg + N);
    uint32* wtU   = (uint32*)(dinv + N);            // 16384 uints (64 KB)
    uint32* Ts1   = wtU + 16384;                    // N*32
    uint32* Rs1   = Ts1 + (size_t)N * 32;           // N*32
    uint32* T2    = Rs1 + (size_t)N * 32;           // N*32
    uint32* R2    = T2 + (size_t)N * 32;            // N*32
    ushort16* wt  = (ushort16*)wtU;

    hipMemsetAsync(bcnt, 0, (size_t)(MAXB + 64 * 64 + 64) * sizeof(int), stream);

    // bucket + fused weight prep
    const int EB = (E + P1_CHUNK - 1) / P1_CHUNK;
    bucket_kernel<<<128 + EB, 256, 0, stream>>>(row, col, bpack, bcnt, E,
                                                w1_init, w1_root, w2_init, w2_root, wt);

    // CSR build + fused layer-1 gemm
    csr_gemm<<<B, 1024, 0, stream>>>(bpack, bcnt, es, nstart, ndeg, dinv,
                                     x, wt, b1, (ushort16*)Ts1, (ushort16*)Rs1, N);

    // gather1 + fused layer-2 gemm
    gather_gemm<<<(N + 63) / 64, 256, 0, stream>>>(
        (const uint2*)Ts1, (const uint2*)Rs1, es, nstart, ndeg, dinv,
        wt + (size_t)4 * 4096, b2, (ushort16*)T2, (ushort16*)R2, N);

    // gather2 + mean-pool (H never materialized)
    gather_pool<<<(N + 63) / 64, 256, 0, stream>>>(
        (const uint2*)T2, (const uint2*)R2, es, nstart, ndeg, dinv,
        batch, pooled, cnt, N);

    // FC
    final_fc<<<(64 * 32 + 255) / 256, 256, 0, stream>>>(pooled, cnt, fc_w, fc_b, out);
}